// Round 7
// baseline (89.486 us; speedup 1.0000x reference)
//
#include <hip/hip_runtime.h>

// NCA update via fp16 MFMA, half-row-per-wave, fully software-pipelined.
// GEMM1: H[o][pix] = W1[o][c] * Y[pix][c] + b[o]   (per 16-px tile: 12x mfma 16x16x32)
// GEMM2: dx[ch][pix] = W2[ch][o] * relu(H)[pix][o] (6x mfma, H stays lane-local)
// Perception: packed-fp16 column-sums + shfl neighbor exchange (circular).
// Pipeline distance 2 covers ALL per-tile global reads: colsum raws, noise.
// Blend-x comes from staged f32 mids via a W2-row permutation (swap bits 2,3)
// so each gq group outputs exactly the channels it staged.
// NOTE: __launch_bounds__(256,4) clamps VGPR to 64 -> spills, 4x slower. Keep (256,2).

#define HH 512
#define WW 512
#define CC 16
#define HID 192
#define NT 16          // tiles per wave (half row: 256 px)
#define HW (HH * WW)

typedef _Float16 half8  __attribute__((ext_vector_type(8)));
typedef _Float16 half2v __attribute__((ext_vector_type(2)));
typedef __fp16   fp16x2 __attribute__((ext_vector_type(2)));
typedef float    f32x4  __attribute__((ext_vector_type(4)));

__device__ __forceinline__ int h2i(half2v v) { return __builtin_bit_cast(int, v); }
__device__ __forceinline__ half2v i2h(int v) { return __builtin_bit_cast(half2v, v); }

__global__ __launch_bounds__(256, 2) void nca_mfma_kernel(
    const float* __restrict__ x,
    const float* __restrict__ noise,
    const float* __restrict__ w1w,
    const float* __restrict__ w1b,
    const float* __restrict__ w2w,
    float* __restrict__ out)
{
    __shared__ __align__(16) float bl[HID];
    const int tid  = threadIdx.x;
    const int lane = tid & 63;
    const int wid  = tid >> 6;
    const int p    = lane & 15;   // pixel-in-tile / matrix row-col index
    const int gq   = lane >> 4;   // fragment k-group

    // XCD-aware swizzle: 1024 blocks -> 8 chunks of 128 consecutive blocks
    const int bid = blockIdx.x;
    const int lin = (bid & 7) * 128 + (bid >> 3);
    const int gr  = lin * 4 + wid;          // half-row id 0..4095
    const int b   = gr >> 10;
    const int rem = gr & 1023;
    const int i   = rem >> 1;               // image row
    const int s   = rem & 1;                // which half
    const int start = s * (WW / 2);

    // stage bias to LDS
    for (int k = tid; k < HID; k += 256) bl[k] = w1b[k];
    __syncthreads();

    // resident W1 A-fragments: lane holds W1[o=16t+p][c=8*gq+e]
    half8 w1f[12];
    #pragma unroll
    for (int t = 0; t < 12; ++t) {
        const float* src = w1w + (16 * t + p) * 32 + 8 * gq;
        #pragma unroll
        for (int e = 0; e < 8; ++e) w1f[t][e] = (_Float16)src[e];
    }
    // resident W2 A-fragments, rows permuted by pi(p)=swap bits2,3:
    // D-row m then holds W2-row pi(m), so gq group stores channels it staged.
    const int pi_p = (p & 3) | ((p & 4) << 1) | ((p & 8) >> 1);
    half8 w2f[6];
    #pragma unroll
    for (int f = 0; f < 6; ++f) {
        const float* s0 = w2w + pi_p * HID + 32 * f + 4 * gq;
        #pragma unroll
        for (int e = 0; e < 4; ++e) {
            w2f[f][e]     = (_Float16)s0[e];
            w2f[f][4 + e] = (_Float16)s0[16 + e];
        }
    }

    const int im = (i == 0) ? HH - 1 : i - 1;
    const int ip = (i == HH - 1) ? 0 : i + 1;
    const float* xb  = x + (size_t)b * CC * HW;
    const int    cb  = 8 * (gq & 1);          // x-channel base for this lane
    const float* xcb = xb + (size_t)cb * HW;
    const int rT = im * WW, rM = i * WW, rB = ip * WW;
    const int eSel = 4 * (gq >> 1);           // which staged mids feed the blend
    const int gqsw = ((gq & 1) << 1) | (gq >> 1);  // store channel group

    // raw loads: 8 channels x 3 rows at column `col` (issue only)
    auto loadRaw = [&](int col, float r[24]) {
        #pragma unroll
        for (int e = 0; e < 8; ++e) {
            const float* pe = xcb + (size_t)e * HW;
            r[3 * e + 0] = pe[rT + col];
            r[3 * e + 1] = pe[rM + col];
            r[3 * e + 2] = pe[rB + col];
        }
    };
    // combine raws -> packed colsums, packed mids, f32 blend mids, ch3 col-max
    auto combine = [&](const float r[24], half2v pcs[4], half2v pm[4],
                       float mx[4], float& cm) {
        #pragma unroll
        for (int w = 0; w < 4; ++w) {
            const float cs0 = r[6 * w + 0] + r[6 * w + 1] + r[6 * w + 2];
            const float cs1 = r[6 * w + 3] + r[6 * w + 4] + r[6 * w + 5];
            pcs[w] = half2v{(_Float16)cs0, (_Float16)cs1};
            pm[w]  = half2v{(_Float16)r[6 * w + 1], (_Float16)r[6 * w + 4]};
        }
        #pragma unroll
        for (int j = 0; j < 4; ++j) mx[j] = r[3 * (eSel + j) + 1];
        cm = fmaxf(fmaxf(r[9], r[10]), r[11]);   // e==3 rows (ch3 for gq 0/2)
    };

    half2v pcsA[4], pcsB[4], pcsC[4], pmB[4], pmC[4];
    float  mxB[4], mxC[4];
    float  cmA, cmB, cmC;
    float  nzB, nzC;
    float  rr[24];

    const float* nrow = noise + (size_t)b * HW + rM;

    // prologue: uniform-column halo (all lanes hold colsum of col start-1)
    {
        float rh[24]; half2v dum[4]; float dmx[4];
        loadRaw((start - 1) & (WW - 1), rh);
        combine(rh, pcsA, dum, dmx, cmA);
        float r0[24];
        loadRaw(start + p, r0);
        combine(r0, pcsB, pmB, mxB, cmB);
        float r1[24];
        loadRaw(start + 16 + p, r1);
        combine(r1, pcsC, pmC, mxC, cmC);
        nzB = nrow[start + p];
        nzC = nrow[start + 16 + p];
    }

    float* ob = out + (size_t)b * CC * HW;
    const f32x4* blv = (const f32x4*)bl;
    const half2v k9 = {(_Float16)9.0f, (_Float16)9.0f};
    const bool isCenter = (gq < 2);

    #pragma unroll 1
    for (int t = 0; t < NT; ++t) {
        // (1) issue raw + noise loads for tile t+2 (masked col; tail iters junk-but-valid)
        const int colP = (start + 16 * (t + 2) + p) & (WW - 1);
        loadRaw(colP, rr);
        const float nzD = nrow[colP];

        // (2) compute tile t ------------------------------------------------
        union { half8 v; int iw[4]; } yf;
        #pragma unroll
        for (int w = 0; w < 4; ++w) {
            const int bw = h2i(pcsB[w]);
            int lft = __shfl_up(bw, 1, 64);
            const int patL = __shfl(h2i(pcsA[w]), lane | 15, 64);
            if (p == 0) lft = patL;
            int rgt = __shfl_down(bw, 1, 64);
            const int patR = __shfl(h2i(pcsC[w]), lane & 48, 64);
            if (p == 15) rgt = patR;
            const half2v s9  = i2h(lft) + pcsB[w] + i2h(rgt);
            const half2v lap = k9 * pmB[w] - s9;
            yf.iw[w] = isCenter ? h2i(pmB[w]) : h2i(lap);
        }

        // alive mask (3x3 circular max of channel 3)
        float ml = __shfl_up(cmB, 1, 64);
        const float pml = __shfl(cmA, lane | 15, 64);
        if (p == 0) ml = pml;
        float mr = __shfl_down(cmB, 1, 64);
        const float pmr = __shfl(cmC, lane & 48, 64);
        if (p == 15) mr = pmr;
        const float rmax  = fmaxf(fmaxf(ml, cmB), mr);
        const float av    = __shfl(rmax, lane & 15, 64);
        const float alive = (av > 0.1f) ? 1.0f : 0.0f;
        const float um    = floorf(nzB + 0.5f);

        // GEMM1 + relu + GEMM2 (H stays lane-local)
        f32x4 acc2a = {0.f, 0.f, 0.f, 0.f}, acc2b = {0.f, 0.f, 0.f, 0.f};
        #pragma unroll
        for (int f = 0; f < 6; ++f) {
            const f32x4 ba = blv[8 * f + gq];
            const f32x4 bb = blv[8 * f + 4 + gq];
            const f32x4 a1 = __builtin_amdgcn_mfma_f32_16x16x32_f16(w1f[2 * f],     yf.v, ba, 0, 0, 0);
            const f32x4 a2 = __builtin_amdgcn_mfma_f32_16x16x32_f16(w1f[2 * f + 1], yf.v, bb, 0, 0, 0);
            union { half8 v; fp16x2 f2[4]; } hf;
            hf.f2[0] = __builtin_amdgcn_cvt_pkrtz(fmaxf(a1[0], 0.f), fmaxf(a1[1], 0.f));
            hf.f2[1] = __builtin_amdgcn_cvt_pkrtz(fmaxf(a1[2], 0.f), fmaxf(a1[3], 0.f));
            hf.f2[2] = __builtin_amdgcn_cvt_pkrtz(fmaxf(a2[0], 0.f), fmaxf(a2[1], 0.f));
            hf.f2[3] = __builtin_amdgcn_cvt_pkrtz(fmaxf(a2[2], 0.f), fmaxf(a2[3], 0.f));
            if (f & 1) acc2b = __builtin_amdgcn_mfma_f32_16x16x32_f16(w2f[f], hf.v, acc2b, 0, 0, 0);
            else       acc2a = __builtin_amdgcn_mfma_f32_16x16x32_f16(w2f[f], hf.v, acc2a, 0, 0, 0);
        }

        // blend + store: lane stores channel 4*gqsw + r at its own column,
        // x comes from the staged f32 mids (no global re-read).
        const int col = start + 16 * t + p;
        #pragma unroll
        for (int r = 0; r < 4; ++r) {
            const size_t off = (size_t)(4 * gqsw + r) * HW + (size_t)rM + col;
            const float dx = acc2a[r] + acc2b[r];
            ob[off] = (mxB[r] + dx * um) * alive;
        }

        // (3) combine tile t+2 raws, rotate pipeline ------------------------
        half2v pcsD[4], pmD[4]; float mxD[4]; float cmD;
        combine(rr, pcsD, pmD, mxD, cmD);
        #pragma unroll
        for (int w = 0; w < 4; ++w) {
            pcsA[w] = pcsB[w];
            pcsB[w] = pcsC[w]; pmB[w] = pmC[w];
            pcsC[w] = pcsD[w]; pmC[w] = pmD[w];
        }
        #pragma unroll
        for (int j = 0; j < 4; ++j) { mxB[j] = mxC[j]; mxC[j] = mxD[j]; }
        cmA = cmB; cmB = cmC; cmC = cmD;
        nzB = nzC; nzC = nzD;
    }
}

extern "C" void kernel_launch(void* const* d_in, const int* in_sizes, int n_in,
                              void* d_out, int out_size, void* d_ws, size_t ws_size,
                              hipStream_t stream)
{
    const float* x     = (const float*)d_in[0];
    const float* noise = (const float*)d_in[1];
    const float* w1w   = (const float*)d_in[2];
    const float* w1b   = (const float*)d_in[3];
    const float* w2w   = (const float*)d_in[4];
    float* out = (float*)d_out;

    nca_mfma_kernel<<<1024, 256, 0, stream>>>(x, noise, w1w, w1b, w2w, out);
}

// Round 8
// 67.876 us; speedup vs baseline: 1.3184x; 1.3184x over previous
//
#include <hip/hip_runtime.h>

// NCA update via fp16 MFMA, half-row-per-wave, fully software-pipelined.
// GEMM1: H[o][pix] = W1[o][c] * Y[pix][c] + b[o]   (per 16-px tile: 12x mfma 16x16x32)
// GEMM2: dx[ch][pix] = W2[ch][o] * relu(H)[pix][o] (6x mfma, H stays lane-local)
// Perception: packed-fp16 column-sums + shfl neighbor exchange (circular).
// Pipeline distance 2 covers ALL per-tile global reads: colsum raws, noise.
// Blend-x comes from staged f32 mids via a W2-row permutation (swap bits 2,3)
// so each gq group outputs exactly the channels it staged.
// RULE-20 FIX: mx extraction uses only compile-time array indices + one
// per-lane select (runtime eSel indexing pushed rr[] out of registers, +22us).
// NOTE: __launch_bounds__(256,4) clamps VGPR to 64 -> spills, 4x slower. Keep (256,2).

#define HH 512
#define WW 512
#define CC 16
#define HID 192
#define NT 16          // tiles per wave (half row: 256 px)
#define HW (HH * WW)

typedef _Float16 half8  __attribute__((ext_vector_type(8)));
typedef _Float16 half2v __attribute__((ext_vector_type(2)));
typedef __fp16   fp16x2 __attribute__((ext_vector_type(2)));
typedef float    f32x4  __attribute__((ext_vector_type(4)));

__device__ __forceinline__ int h2i(half2v v) { return __builtin_bit_cast(int, v); }
__device__ __forceinline__ half2v i2h(int v) { return __builtin_bit_cast(half2v, v); }

__global__ __launch_bounds__(256, 2) void nca_mfma_kernel(
    const float* __restrict__ x,
    const float* __restrict__ noise,
    const float* __restrict__ w1w,
    const float* __restrict__ w1b,
    const float* __restrict__ w2w,
    float* __restrict__ out)
{
    __shared__ __align__(16) float bl[HID];
    const int tid  = threadIdx.x;
    const int lane = tid & 63;
    const int wid  = tid >> 6;
    const int p    = lane & 15;   // pixel-in-tile / matrix row-col index
    const int gq   = lane >> 4;   // fragment k-group

    // XCD-aware swizzle: 1024 blocks -> 8 chunks of 128 consecutive blocks
    const int bid = blockIdx.x;
    const int lin = (bid & 7) * 128 + (bid >> 3);
    const int gr  = lin * 4 + wid;          // half-row id 0..4095
    const int b   = gr >> 10;
    const int rem = gr & 1023;
    const int i   = rem >> 1;               // image row
    const int s   = rem & 1;                // which half
    const int start = s * (WW / 2);

    // stage bias to LDS
    for (int k = tid; k < HID; k += 256) bl[k] = w1b[k];
    __syncthreads();

    // resident W1 A-fragments: lane holds W1[o=16t+p][c=8*gq+e]
    half8 w1f[12];
    #pragma unroll
    for (int t = 0; t < 12; ++t) {
        const float* src = w1w + (16 * t + p) * 32 + 8 * gq;
        #pragma unroll
        for (int e = 0; e < 8; ++e) w1f[t][e] = (_Float16)src[e];
    }
    // resident W2 A-fragments, rows permuted by pi(p)=swap bits2,3:
    // D-row m then holds W2-row pi(m), so gq group stores channels it staged.
    const int pi_p = (p & 3) | ((p & 4) << 1) | ((p & 8) >> 1);
    half8 w2f[6];
    #pragma unroll
    for (int f = 0; f < 6; ++f) {
        const float* s0 = w2w + pi_p * HID + 32 * f + 4 * gq;
        #pragma unroll
        for (int e = 0; e < 4; ++e) {
            w2f[f][e]     = (_Float16)s0[e];
            w2f[f][4 + e] = (_Float16)s0[16 + e];
        }
    }

    const int im = (i == 0) ? HH - 1 : i - 1;
    const int ip = (i == HH - 1) ? 0 : i + 1;
    const float* xb  = x + (size_t)b * CC * HW;
    const int    cb  = 8 * (gq & 1);          // x-channel base for this lane
    const float* xcb = xb + (size_t)cb * HW;
    const int rT = im * WW, rM = i * WW, rB = ip * WW;
    const bool hiSel = (gq >= 2);             // blend mids from e=4..7?
    const int gqsw = ((gq & 1) << 1) | (gq >> 1);  // store channel group

    // raw loads: 8 channels x 3 rows at column `col` (issue only)
    auto loadRaw = [&](int col, float r[24]) {
        #pragma unroll
        for (int e = 0; e < 8; ++e) {
            const float* pe = xcb + (size_t)e * HW;
            r[3 * e + 0] = pe[rT + col];
            r[3 * e + 1] = pe[rM + col];
            r[3 * e + 2] = pe[rB + col];
        }
    };
    // combine raws -> packed colsums, packed mids, f32 blend mids, ch3 col-max
    // (ALL array indices compile-time constant; hiSel resolved by cndmask)
    auto combine = [&](const float r[24], half2v pcs[4], half2v pm[4],
                       float mx[4], float& cm) {
        #pragma unroll
        for (int w = 0; w < 4; ++w) {
            const float cs0 = r[6 * w + 0] + r[6 * w + 1] + r[6 * w + 2];
            const float cs1 = r[6 * w + 3] + r[6 * w + 4] + r[6 * w + 5];
            pcs[w] = half2v{(_Float16)cs0, (_Float16)cs1};
            pm[w]  = half2v{(_Float16)r[6 * w + 1], (_Float16)r[6 * w + 4]};
        }
        #pragma unroll
        for (int j = 0; j < 4; ++j)
            mx[j] = hiSel ? r[3 * (j + 4) + 1] : r[3 * j + 1];
        cm = fmaxf(fmaxf(r[9], r[10]), r[11]);   // e==3 rows (ch3 for gq 0/2)
    };

    half2v pcsA[4], pcsB[4], pcsC[4], pmB[4], pmC[4];
    float  mxB[4], mxC[4];
    float  cmA, cmB, cmC;
    float  nzB, nzC;
    float  rr[24];

    const float* nrow = noise + (size_t)b * HW + rM;

    // prologue: uniform-column halo (all lanes hold colsum of col start-1)
    {
        float rh[24]; half2v dum[4]; float dmx[4];
        loadRaw((start - 1) & (WW - 1), rh);
        combine(rh, pcsA, dum, dmx, cmA);
        float r0[24];
        loadRaw(start + p, r0);
        combine(r0, pcsB, pmB, mxB, cmB);
        float r1[24];
        loadRaw(start + 16 + p, r1);
        combine(r1, pcsC, pmC, mxC, cmC);
        nzB = nrow[start + p];
        nzC = nrow[start + 16 + p];
    }

    float* ob = out + (size_t)b * CC * HW;
    const f32x4* blv = (const f32x4*)bl;
    const half2v k9 = {(_Float16)9.0f, (_Float16)9.0f};
    const bool isCenter = (gq < 2);

    #pragma unroll 1
    for (int t = 0; t < NT; ++t) {
        // (1) issue raw + noise loads for tile t+2 (masked col; tail iters junk-but-valid)
        const int colP = (start + 16 * (t + 2) + p) & (WW - 1);
        loadRaw(colP, rr);
        const float nzD = nrow[colP];

        // (2) compute tile t ------------------------------------------------
        union { half8 v; int iw[4]; } yf;
        #pragma unroll
        for (int w = 0; w < 4; ++w) {
            const int bw = h2i(pcsB[w]);
            int lft = __shfl_up(bw, 1, 64);
            const int patL = __shfl(h2i(pcsA[w]), lane | 15, 64);
            if (p == 0) lft = patL;
            int rgt = __shfl_down(bw, 1, 64);
            const int patR = __shfl(h2i(pcsC[w]), lane & 48, 64);
            if (p == 15) rgt = patR;
            const half2v s9  = i2h(lft) + pcsB[w] + i2h(rgt);
            const half2v lap = k9 * pmB[w] - s9;
            yf.iw[w] = isCenter ? h2i(pmB[w]) : h2i(lap);
        }

        // alive mask (3x3 circular max of channel 3)
        float ml = __shfl_up(cmB, 1, 64);
        const float pml = __shfl(cmA, lane | 15, 64);
        if (p == 0) ml = pml;
        float mr = __shfl_down(cmB, 1, 64);
        const float pmr = __shfl(cmC, lane & 48, 64);
        if (p == 15) mr = pmr;
        const float rmax  = fmaxf(fmaxf(ml, cmB), mr);
        const float av    = __shfl(rmax, lane & 15, 64);
        const float alive = (av > 0.1f) ? 1.0f : 0.0f;
        const float um    = floorf(nzB + 0.5f);

        // GEMM1 + relu + GEMM2 (H stays lane-local)
        f32x4 acc2a = {0.f, 0.f, 0.f, 0.f}, acc2b = {0.f, 0.f, 0.f, 0.f};
        #pragma unroll
        for (int f = 0; f < 6; ++f) {
            const f32x4 ba = blv[8 * f + gq];
            const f32x4 bb = blv[8 * f + 4 + gq];
            const f32x4 a1 = __builtin_amdgcn_mfma_f32_16x16x32_f16(w1f[2 * f],     yf.v, ba, 0, 0, 0);
            const f32x4 a2 = __builtin_amdgcn_mfma_f32_16x16x32_f16(w1f[2 * f + 1], yf.v, bb, 0, 0, 0);
            union { half8 v; fp16x2 f2[4]; } hf;
            hf.f2[0] = __builtin_amdgcn_cvt_pkrtz(fmaxf(a1[0], 0.f), fmaxf(a1[1], 0.f));
            hf.f2[1] = __builtin_amdgcn_cvt_pkrtz(fmaxf(a1[2], 0.f), fmaxf(a1[3], 0.f));
            hf.f2[2] = __builtin_amdgcn_cvt_pkrtz(fmaxf(a2[0], 0.f), fmaxf(a2[1], 0.f));
            hf.f2[3] = __builtin_amdgcn_cvt_pkrtz(fmaxf(a2[2], 0.f), fmaxf(a2[3], 0.f));
            if (f & 1) acc2b = __builtin_amdgcn_mfma_f32_16x16x32_f16(w2f[f], hf.v, acc2b, 0, 0, 0);
            else       acc2a = __builtin_amdgcn_mfma_f32_16x16x32_f16(w2f[f], hf.v, acc2a, 0, 0, 0);
        }

        // blend + store: lane stores channel 4*gqsw + r at its own column,
        // x comes from the staged f32 mids (no global re-read).
        const int col = start + 16 * t + p;
        #pragma unroll
        for (int r = 0; r < 4; ++r) {
            const size_t off = (size_t)(4 * gqsw + r) * HW + (size_t)rM + col;
            const float dx = acc2a[r] + acc2b[r];
            ob[off] = (mxB[r] + dx * um) * alive;
        }

        // (3) combine tile t+2 raws, rotate pipeline ------------------------
        half2v pcsD[4], pmD[4]; float mxD[4]; float cmD;
        combine(rr, pcsD, pmD, mxD, cmD);
        #pragma unroll
        for (int w = 0; w < 4; ++w) {
            pcsA[w] = pcsB[w];
            pcsB[w] = pcsC[w]; pmB[w] = pmC[w];
            pcsC[w] = pcsD[w]; pmC[w] = pmD[w];
        }
        #pragma unroll
        for (int j = 0; j < 4; ++j) { mxB[j] = mxC[j]; mxC[j] = mxD[j]; }
        cmA = cmB; cmB = cmC; cmC = cmD;
        nzB = nzC; nzC = nzD;
    }
}

extern "C" void kernel_launch(void* const* d_in, const int* in_sizes, int n_in,
                              void* d_out, int out_size, void* d_ws, size_t ws_size,
                              hipStream_t stream)
{
    const float* x     = (const float*)d_in[0];
    const float* noise = (const float*)d_in[1];
    const float* w1w   = (const float*)d_in[2];
    const float* w1b   = (const float*)d_in[3];
    const float* w2w   = (const float*)d_in[4];
    float* out = (float*)d_out;

    nca_mfma_kernel<<<1024, 256, 0, stream>>>(x, noise, w1w, w1b, w2w, out);
}

// Round 9
// 64.977 us; speedup vs baseline: 1.3772x; 1.0446x over previous
//
#include <hip/hip_runtime.h>

// NCA update via fp16 MFMA, half-row-per-wave, fully software-pipelined.
// GEMM1: H[o][pix] = W1[o][c] * Y[pix][c] + b[o]   (per 16-px tile: 12x mfma 16x16x32)
// GEMM2: dx[ch][pix] = W2[ch][o] * relu(H)[pix][o] (6x mfma, H stays lane-local)
// Perception: packed-fp16 column-sums + shfl neighbor exchange (circular).
// Pipeline distance 2 covers ALL per-tile global reads: colsum raws, noise.
// Blend-x from staged f32 mids via W2-row permutation (swap bits 2,3).
// R9: readfirstlane scalarizes row/base addressing (saddr loads, 1 shared
// voffset), cvt_pkrtz packing in combine, unroll-4 for rotate-by-renaming.
// NOTE: __launch_bounds__(256,4) clamps VGPR to 64 -> spills, 4x slower. Keep (256,2).

#define HH 512
#define WW 512
#define CC 16
#define HID 192
#define NT 16          // tiles per wave (half row: 256 px)
#define HW (HH * WW)

typedef _Float16 half8  __attribute__((ext_vector_type(8)));
typedef _Float16 half2v __attribute__((ext_vector_type(2)));
typedef __fp16   fp16x2 __attribute__((ext_vector_type(2)));
typedef float    f32x4  __attribute__((ext_vector_type(4)));

__device__ __forceinline__ int h2i(half2v v) { return __builtin_bit_cast(int, v); }
__device__ __forceinline__ half2v i2h(int v) { return __builtin_bit_cast(half2v, v); }
__device__ __forceinline__ int f2i(fp16x2 v) { return __builtin_bit_cast(int, v); }

__global__ __launch_bounds__(256, 2) void nca_mfma_kernel(
    const float* __restrict__ x,
    const float* __restrict__ noise,
    const float* __restrict__ w1w,
    const float* __restrict__ w1b,
    const float* __restrict__ w2w,
    float* __restrict__ out)
{
    __shared__ __align__(16) float bl[HID];
    const int tid  = threadIdx.x;
    const int lane = tid & 63;
    const int wid  = tid >> 6;
    const int p    = lane & 15;   // pixel-in-tile / matrix row-col index
    const int gq   = lane >> 4;   // fragment k-group

    // XCD-aware swizzle: 1024 blocks -> 8 chunks of 128 consecutive blocks
    const int bid = blockIdx.x;
    const int lin = (bid & 7) * 128 + (bid >> 3);
    // wave-uniform scalars, forced into SGPRs
    const int gr    = __builtin_amdgcn_readfirstlane(lin * 4 + wid); // half-row id
    const int b     = gr >> 10;
    const int rem   = gr & 1023;
    const int i     = rem >> 1;             // image row
    const int start = (rem & 1) * (WW / 2); // which half

    // stage bias to LDS
    for (int k = tid; k < HID; k += 256) bl[k] = w1b[k];
    __syncthreads();

    // resident W1 A-fragments: lane holds W1[o=16t+p][c=8*gq+e]
    half8 w1f[12];
    #pragma unroll
    for (int t = 0; t < 12; ++t) {
        const float* src = w1w + (16 * t + p) * 32 + 8 * gq;
        #pragma unroll
        for (int e = 0; e < 8; ++e) w1f[t][e] = (_Float16)src[e];
    }
    // resident W2 A-fragments, rows permuted by pi(p)=swap bits2,3:
    // D-row m then holds W2-row pi(m), so gq group stores channels it staged.
    const int pi_p = (p & 3) | ((p & 4) << 1) | ((p & 8) >> 1);
    half8 w2f[6];
    #pragma unroll
    for (int f = 0; f < 6; ++f) {
        const float* s0 = w2w + pi_p * HID + 32 * f + 4 * gq;
        #pragma unroll
        for (int e = 0; e < 4; ++e) {
            w2f[f][e]     = (_Float16)s0[e];
            w2f[f][4 + e] = (_Float16)s0[16 + e];
        }
    }

    const int im = (i == 0) ? HH - 1 : i - 1;
    const int ip = (i == HH - 1) ? 0 : i + 1;
    const int rT = im * WW, rM = i * WW, rB = ip * WW;
    // uniform row-base pointers (SGPR pairs); per-lane part is col only
    const float* xbch = x + ((size_t)b * CC + 8 * (gq & 1)) * HW;  // gq-uniform too
    const float* pT = xbch + rT;
    const float* pM = xbch + rM;
    const float* pB = xbch + rB;
    const float* nrow = noise + (size_t)b * HW + rM;
    float* orow = out + (size_t)b * CC * HW + rM;

    const bool hiSel = (gq >= 2);             // blend mids from e=4..7?
    const int gqsw = ((gq & 1) << 1) | (gq >> 1);  // store channel group

    // raw loads: 8 channels x 3 rows at column `col` (uniform base + col)
    auto loadRaw = [&](int col, float r[24]) {
        #pragma unroll
        for (int e = 0; e < 8; ++e) {
            r[3 * e + 0] = pT[e * HW + col];
            r[3 * e + 1] = pM[e * HW + col];
            r[3 * e + 2] = pB[e * HW + col];
        }
    };
    // combine raws -> packed colsums, packed mids, f32 blend mids, ch3 col-max
    auto combine = [&](const float r[24], half2v pcs[4], half2v pm[4],
                       float mx[4], float& cm) {
        #pragma unroll
        for (int w = 0; w < 4; ++w) {
            const float cs0 = r[6 * w + 0] + r[6 * w + 1] + r[6 * w + 2];
            const float cs1 = r[6 * w + 3] + r[6 * w + 4] + r[6 * w + 5];
            pcs[w] = i2h(f2i(__builtin_amdgcn_cvt_pkrtz(cs0, cs1)));
            pm[w]  = i2h(f2i(__builtin_amdgcn_cvt_pkrtz(r[6 * w + 1], r[6 * w + 4])));
        }
        #pragma unroll
        for (int j = 0; j < 4; ++j)
            mx[j] = hiSel ? r[3 * (j + 4) + 1] : r[3 * j + 1];
        cm = fmaxf(fmaxf(r[9], r[10]), r[11]);   // e==3 rows (ch3 for gq 0/2)
    };

    half2v pcsA[4], pcsB[4], pcsC[4], pmB[4], pmC[4];
    float  mxB[4], mxC[4];
    float  cmA, cmB, cmC;
    float  nzB, nzC;
    float  rr[24];

    // prologue: uniform-column halo (all lanes hold colsum of col start-1)
    {
        float rh[24]; half2v dum[4]; float dmx[4];
        loadRaw((start - 1) & (WW - 1), rh);
        combine(rh, pcsA, dum, dmx, cmA);
        float r0[24];
        loadRaw(start + p, r0);
        combine(r0, pcsB, pmB, mxB, cmB);
        float r1[24];
        loadRaw(start + 16 + p, r1);
        combine(r1, pcsC, pmC, mxC, cmC);
        nzB = nrow[start + p];
        nzC = nrow[start + 16 + p];
    }

    const f32x4* blv = (const f32x4*)bl;
    const half2v k9 = {(_Float16)9.0f, (_Float16)9.0f};
    const bool isCenter = (gq < 2);

    #pragma unroll 4
    for (int t = 0; t < NT; ++t) {
        // (1) issue raw + noise loads for tile t+2 (masked col; tail iters junk-but-valid)
        const int colP = (start + 16 * (t + 2) + p) & (WW - 1);
        loadRaw(colP, rr);
        const float nzD = nrow[colP];

        // (2) compute tile t ------------------------------------------------
        union { half8 v; int iw[4]; } yf;
        #pragma unroll
        for (int w = 0; w < 4; ++w) {
            const int bw = h2i(pcsB[w]);
            int lft = __shfl_up(bw, 1, 64);
            const int patL = __shfl(h2i(pcsA[w]), lane | 15, 64);
            if (p == 0) lft = patL;
            int rgt = __shfl_down(bw, 1, 64);
            const int patR = __shfl(h2i(pcsC[w]), lane & 48, 64);
            if (p == 15) rgt = patR;
            const half2v s9  = i2h(lft) + pcsB[w] + i2h(rgt);
            const half2v lap = k9 * pmB[w] - s9;
            yf.iw[w] = isCenter ? h2i(pmB[w]) : h2i(lap);
        }

        // alive mask (3x3 circular max of channel 3)
        float ml = __shfl_up(cmB, 1, 64);
        const float pml = __shfl(cmA, lane | 15, 64);
        if (p == 0) ml = pml;
        float mr = __shfl_down(cmB, 1, 64);
        const float pmr = __shfl(cmC, lane & 48, 64);
        if (p == 15) mr = pmr;
        const float rmax  = fmaxf(fmaxf(ml, cmB), mr);
        const float av    = __shfl(rmax, lane & 15, 64);
        const float alive = (av > 0.1f) ? 1.0f : 0.0f;
        const float um    = floorf(nzB + 0.5f);

        // GEMM1 + relu + GEMM2 (H stays lane-local)
        f32x4 acc2a = {0.f, 0.f, 0.f, 0.f}, acc2b = {0.f, 0.f, 0.f, 0.f};
        #pragma unroll
        for (int f = 0; f < 6; ++f) {
            const f32x4 ba = blv[8 * f + gq];
            const f32x4 bb = blv[8 * f + 4 + gq];
            const f32x4 a1 = __builtin_amdgcn_mfma_f32_16x16x32_f16(w1f[2 * f],     yf.v, ba, 0, 0, 0);
            const f32x4 a2 = __builtin_amdgcn_mfma_f32_16x16x32_f16(w1f[2 * f + 1], yf.v, bb, 0, 0, 0);
            union { half8 v; fp16x2 f2[4]; } hf;
            hf.f2[0] = __builtin_amdgcn_cvt_pkrtz(fmaxf(a1[0], 0.f), fmaxf(a1[1], 0.f));
            hf.f2[1] = __builtin_amdgcn_cvt_pkrtz(fmaxf(a1[2], 0.f), fmaxf(a1[3], 0.f));
            hf.f2[2] = __builtin_amdgcn_cvt_pkrtz(fmaxf(a2[0], 0.f), fmaxf(a2[1], 0.f));
            hf.f2[3] = __builtin_amdgcn_cvt_pkrtz(fmaxf(a2[2], 0.f), fmaxf(a2[3], 0.f));
            if (f & 1) acc2b = __builtin_amdgcn_mfma_f32_16x16x32_f16(w2f[f], hf.v, acc2b, 0, 0, 0);
            else       acc2a = __builtin_amdgcn_mfma_f32_16x16x32_f16(w2f[f], hf.v, acc2a, 0, 0, 0);
        }

        // blend + store: lane stores channel 4*gqsw + r at its own column,
        // x comes from the staged f32 mids (no global re-read).
        const int col = start + 16 * t + p;
        #pragma unroll
        for (int r = 0; r < 4; ++r) {
            const float dx = acc2a[r] + acc2b[r];
            orow[(size_t)(4 * gqsw + r) * HW + col] = (mxB[r] + dx * um) * alive;
        }

        // (3) combine tile t+2 raws, rotate pipeline ------------------------
        half2v pcsD[4], pmD[4]; float mxD[4]; float cmD;
        combine(rr, pcsD, pmD, mxD, cmD);
        #pragma unroll
        for (int w = 0; w < 4; ++w) {
            pcsA[w] = pcsB[w];
            pcsB[w] = pcsC[w]; pmB[w] = pmC[w];
            pcsC[w] = pcsD[w]; pmC[w] = pmD[w];
        }
        #pragma unroll
        for (int j = 0; j < 4; ++j) { mxB[j] = mxC[j]; mxC[j] = mxD[j]; }
        cmA = cmB; cmB = cmC; cmC = cmD;
        nzB = nzC; nzC = nzD;
    }
}

extern "C" void kernel_launch(void* const* d_in, const int* in_sizes, int n_in,
                              void* d_out, int out_size, void* d_ws, size_t ws_size,
                              hipStream_t stream)
{
    const float* x     = (const float*)d_in[0];
    const float* noise = (const float*)d_in[1];
    const float* w1w   = (const float*)d_in[2];
    const float* w1b   = (const float*)d_in[3];
    const float* w2w   = (const float*)d_in[4];
    float* out = (float*)d_out;

    nca_mfma_kernel<<<1024, 256, 0, stream>>>(x, noise, w1w, w1b, w2w, out);
}